// Round 15
// baseline (231.011 us; speedup 1.0000x reference)
//
#include <hip/hip_runtime.h>
#include <hip/hip_bf16.h>
#include <stdint.h>

// C = (B,16,16): diag (k,k)=sigmoid(x·Wd[k]+bd[k]); off (i,j)=-softplus(x·Wo[r]+bo[r])
// Permuted GEMM out[b][c], c=i*16+j. M=65536 N=256 K=1024, bf16 MFMA 16x16x32.
// R15: max-TLP independent waves. 1024 blocks x 256 thr, launch_bounds(256,4)
// -> 16 waves/CU, 4 independent streams/SIMD. Wave = 16 rows x 256 cols:
// acc 64 VGPR, A-prefetch 8 regs (one m-frag -> no register-pressure sink),
// B direct from L2-resident fragment-ordered image (4 waves/block self-align
// -> L1 hits). ZERO barriers in the main loop; epilogue = R8-verified banded
// LDS transpose -> contiguous float4 row stores.

typedef __bf16 bf16x8 __attribute__((ext_vector_type(8)));
typedef float f32x4 __attribute__((ext_vector_type(4)));

#define THREADS 256
#define WBYTES 524288              // 32 chunk-images x 16 KB (fragment order)

__device__ __forceinline__ unsigned bf_rtne(unsigned u) {
  return (u + 0x7fffu + ((u >> 16) & 1u)) >> 16;
}
__device__ __forceinline__ unsigned pack2(float lo, float hi) {
  return bf_rtne(__float_as_uint(lo)) | (bf_rtne(__float_as_uint(hi)) << 16);
}
__device__ __forceinline__ bf16x8 packfrag(const float4& a, const float4& b) {
  uint4 u;
  u.x = pack2(a.x, a.y); u.y = pack2(a.z, a.w);
  u.z = pack2(b.x, b.y); u.w = pack2(b.z, b.w);
  return *reinterpret_cast<bf16x8*>(&u);
}

// W image, fragment order (R8/R13-verified): (c,k): ch=k>>5, q=(k>>3)&3, e=k&7
// byte = ch*16384 + q*4096 + c*16 + e*2 ; wave B-frag = 4 x 256B segments.
__global__ void prep_kernel(const float* __restrict__ Wd, const float* __restrict__ bd,
                            const float* __restrict__ Wo, const float* __restrict__ bo,
                            char* __restrict__ wbuf, float* __restrict__ bias) {
  const int c = blockIdx.x;    // 0..255 output col
  const int t = threadIdx.x;   // 0..255, 4 consecutive k each
  const int i = c >> 4, j = c & 15;
  const float* src;
  float b;
  if (i == j) { src = Wd + i * 1024; b = bd[i]; }
  else { int r = i * 15 + (j < i ? j : j - 1); src = Wo + r * 1024; b = bo[r]; }
  if (t == 0) bias[c] = b;
  const int kk = t * 4;
  const int ch = kk >> 5, q = (kk >> 3) & 3, e = kk & 7;
  float4 v = *reinterpret_cast<const float4*>(src + kk);
  uint2 h;
  h.x = pack2(v.x, v.y);
  h.y = pack2(v.z, v.w);
  *reinterpret_cast<uint2*>(wbuf + ch * 16384 + q * 4096 + c * 16 + e * 2) = h;
}

__global__ __launch_bounds__(THREADS, 4) void cap_main(
    const float* __restrict__ x, const char* __restrict__ wbuf,
    const float* __restrict__ bias, float* __restrict__ out) {
  __shared__ char smem[16640];   // epilogue only: 16 rows x 1040 B

  const int tid = threadIdx.x;
  const int wid = tid >> 6;      // wave 0..3 (independent until epilogue)
  const int lane = tid & 63;
  const int l15 = lane & 15;
  const int l4 = lane >> 4;

  // wave owns rows wr0..wr0+15, all 256 cols
  const size_t wr0 = ((size_t)blockIdx.x * 4 + wid) * 16;
  const float* xb = x + (wr0 + (size_t)l15) * 1024 + l4 * 8;   // + c*32 floats
  const char* wb = wbuf + l4 * 4096 + l15 * 16;                // + ch*16384 + n*256

  f32x4 acc[16];
#pragma unroll
  for (int n = 0; n < 16; ++n) acc[n] = (f32x4){0.f, 0.f, 0.f, 0.f};

  // A prefetch regs (one chunk = 8 floats/lane)
  float4 c0 = *reinterpret_cast<const float4*>(xb);
  float4 c1 = *reinterpret_cast<const float4*>(xb + 4);

#pragma unroll 2
  for (int c = 0; c < 32; ++c) {
    bf16x8 af = packfrag(c0, c1);

    // issue next chunk's 2 loads before the MFMAs (light pressure: 8 regs)
    const int cn = (c + 1 < 32) ? c + 1 : 31;
    const float* xp = xb + cn * 32;
    float4 n0 = *reinterpret_cast<const float4*>(xp);
    float4 n1 = *reinterpret_cast<const float4*>(xp + 4);

    const char* wc = wb + c * 16384;
#pragma unroll
    for (int n = 0; n < 16; ++n) {
      uint4 bu = *reinterpret_cast<const uint4*>(wc + n * 256);
      acc[n] = __builtin_amdgcn_mfma_f32_16x16x32_bf16(
          af, *reinterpret_cast<bf16x8*>(&bu), acc[n], 0, 0, 0);
    }
    c0 = n0; c1 = n1;
  }

  // ---- epilogue: bias + activation -> banded LDS transpose (R8-verified) ----
  float bv[16];
#pragma unroll
  for (int n = 0; n < 16; ++n) bv[n] = bias[n * 16 + l15];

  const int rr = tid >> 4;        // 0..15 read-back row in band
  const int cg = tid & 15;        // 16-float col group
  const char* rdp = smem + rr * 1040 + cg * 64;

  __syncthreads();

#pragma unroll
  for (int p = 0; p < 4; ++p) {   // band p = wave p's 16 rows
    if (wid == p) {
#pragma unroll
      for (int n = 0; n < 16; ++n) {
        const int col = n * 16 + l15;
        const bool diag = (col % 17) == 0;
#pragma unroll
        for (int j2 = 0; j2 < 4; ++j2) {
          float v = acc[n][j2] + bv[n];
          float e = __expf(-fabsf(v));
          float sig = (v >= 0.f) ? 1.f / (1.f + e) : e / (1.f + e);
          float sp = fmaxf(v, 0.f) + __logf(1.f + e);
          *reinterpret_cast<float*>(smem + (l4 * 4 + j2) * 1040 + col * 4) =
              diag ? sig : -sp;
        }
      }
    }
    __syncthreads();
    float4 o0 = *reinterpret_cast<const float4*>(rdp);
    float4 o1 = *reinterpret_cast<const float4*>(rdp + 16);
    float4 o2 = *reinterpret_cast<const float4*>(rdp + 32);
    float4 o3 = *reinterpret_cast<const float4*>(rdp + 48);
    float* orow = out + ((size_t)blockIdx.x * 64 + p * 16 + rr) * 256 + cg * 16;
    *reinterpret_cast<float4*>(orow) = o0;
    *reinterpret_cast<float4*>(orow + 4) = o1;
    *reinterpret_cast<float4*>(orow + 8) = o2;
    *reinterpret_cast<float4*>(orow + 12) = o3;
    __syncthreads();
  }
}

extern "C" void kernel_launch(void* const* d_in, const int* in_sizes, int n_in,
                              void* d_out, int out_size, void* d_ws, size_t ws_size,
                              hipStream_t stream) {
  const float* x = (const float*)d_in[0];
  const float* Wd = (const float*)d_in[1];
  const float* bd = (const float*)d_in[2];
  const float* Wo = (const float*)d_in[3];
  const float* bo = (const float*)d_in[4];
  float* out = (float*)d_out;
  char* wbuf = (char*)d_ws;                  // 512 KiB weight image
  float* bias = (float*)(wbuf + WBYTES);     // 1 KiB bias

  prep_kernel<<<dim3(256), dim3(256), 0, stream>>>(Wd, bd, Wo, bo, wbuf, bias);
  cap_main<<<dim3(1024), dim3(THREADS), 0, stream>>>(x, wbuf, bias, out);
}

// Round 17
// 103.032 us; speedup vs baseline: 2.2421x; 2.2421x over previous
//
#include <hip/hip_runtime.h>
#include <hip/hip_bf16.h>
#include <stdint.h>

// C = (B,16,16): diag (k,k)=sigmoid(x·Wd[k]+bd[k]); off (i,j)=-softplus(x·Wo[r]+bo[r])
// Permuted GEMM out[b][c], c=i*16+j. M=65536 N=256 K=1024, bf16 MFMA 16x16x32.
// R17: R16 with fixed staging arithmetic (R16 wrote LDS out of bounds).
// BM=128, 512 blocks x 512 thr (8 waves, 2Mx4N). Per-block x 512 KB + B 512 KB
// -> per-CU lifetime 2 MB (BM=64 designs: 3 MB). A fp32 via gload_lds (3-slot
// ring, 2-step HBM cover, pre-swizzled source); B via gload_lds (2-slot ring,
// 1-step L2 cover, image pre-swizzled). Per step: issue B(t+1) then A(t+2);
// after MFMA wait vmcnt(2) = retire A(t+1)+B(t+1), keep A(t+2) in flight
// across the raw barrier. LDS 80 KB -> 2 blocks/CU; launch_bounds(512,4).

typedef __bf16 bf16x8 __attribute__((ext_vector_type(8)));
typedef float f32x4 __attribute__((ext_vector_type(4)));

#define THREADS 512
#define BM 128
#define KSTEPS 32
#define WIMG 16384                 // per-K-step B image: 256 cols x 32 k x 2B
#define WBYTES (WIMG * KSTEPS)     // 512 KiB

#define ASLOT 16384                // A slot: 128 rows x 32 k x 4B fp32 (swizzled)
#define BBASE 49152                // A slots @0,16K,32K ; B slots @48K,64K
#define BSLOT 16384
#define SMEM_SZ 81920              // 80 KiB -> 2 blocks/CU

__device__ __forceinline__ unsigned bf_rtne(unsigned u) {
  return (u + 0x7fffu + ((u >> 16) & 1u)) >> 16;
}
__device__ __forceinline__ unsigned pack2(float lo, float hi) {
  return bf_rtne(__float_as_uint(lo)) | (bf_rtne(__float_as_uint(hi)) << 16);
}
__device__ __forceinline__ bf16x8 packfrag(const f32x4& a, const f32x4& b) {
  uint4 u;
  u.x = pack2(a[0], a[1]); u.y = pack2(a[2], a[3]);
  u.z = pack2(b[0], b[1]); u.w = pack2(b[2], b[3]);
  return *reinterpret_cast<bf16x8*>(&u);
}
__device__ __forceinline__ void gload_lds16(const void* g, void* l) {
  __builtin_amdgcn_global_load_lds(
      (const __attribute__((address_space(1))) unsigned int*)g,
      (__attribute__((address_space(3))) unsigned int*)l, 16, 0, 0);
}

// B image per K-step (R4/R12-verified): byte(c,k)=(c*64+k*2)^(((c>>1)&3)<<4)
__global__ void prep_kernel(const float* __restrict__ Wd, const float* __restrict__ bd,
                            const float* __restrict__ Wo, const float* __restrict__ bo,
                            char* __restrict__ wbuf, float* __restrict__ bias) {
  const int c = blockIdx.x;    // 0..255 output col
  const int t = threadIdx.x;   // 0..255, 4 consecutive k each
  const int i = c >> 4, j = c & 15;
  const float* src;
  float b;
  if (i == j) { src = Wd + i * 1024; b = bd[i]; }
  else { int r = i * 15 + (j < i ? j : j - 1); src = Wo + r * 1024; b = bo[r]; }
  if (t == 0) bias[c] = b;
  const int kk = t * 4;
  const int img = kk >> 5, k5 = kk & 31;
  float4 v = *reinterpret_cast<const float4*>(src + kk);
  uint2 h;
  h.x = pack2(v.x, v.y);
  h.y = pack2(v.z, v.w);
  const unsigned off = (unsigned)((c * 64 + k5 * 2) ^ (((c >> 1) & 3) << 4));
  *reinterpret_cast<uint2*>(wbuf + img * WIMG + off) = h;
}

__global__ __launch_bounds__(THREADS, 4) void cap_main(
    const float* __restrict__ x, const char* __restrict__ wbuf,
    const float* __restrict__ bias, float* __restrict__ out) {
  __shared__ char smem[SMEM_SZ];

  const int tid = threadIdx.x;
  const int wid = tid >> 6;
  const int lane = tid & 63;
  const int l15 = lane & 15;
  const int l4 = lane >> 4;
  const int wm = wid >> 2;       // 0..1: rows wm*64..+63
  const int wn = wid & 3;        // 0..3: cols wn*64..+63

  const size_t blkRow = (size_t)blockIdx.x * BM;

  // ---- A staging map (2 insts/thread; 512 thr x 16B x 2 = 16 KB slot) ----
  // inst i: dest d = i*8192 + tid*16 ; row = i*64 + (tid>>3) ; col = (tid&7)*16
  // LDS layout byte(row,kb) = row*128 + (kb ^ ((row&7)<<4)) -> pre-swizzle src.
  const unsigned acol = (unsigned)(((tid & 7) * 16) ^ (((tid >> 3) & 7) << 4));
  const char* asrc[2];
  unsigned adst[2];
#pragma unroll
  for (int i = 0; i < 2; ++i) {
    const int row = i * 64 + (tid >> 3);
    asrc[i] = (const char*)(x + (blkRow + (size_t)row) * 1024) + acol;
    adst[i] = (unsigned)(i * 8192 + tid * 16);
  }

  // ---- fragment read bases ----
  const unsigned swA = (unsigned)((l15 & 7) << 4);
  // B: col c = wn*64+n*16+l15 -> byte = wn*4096 + n*1024 + l15*64 + (l4*16 ^ swB)
  const unsigned bbase = (unsigned)(wn * 4096 + l15 * 64 +
                                    ((l4 * 16) ^ (((l15 >> 1) & 3) << 4)));

  f32x4 acc[4][4];
#pragma unroll
  for (int m = 0; m < 4; ++m)
#pragma unroll
    for (int n = 0; n < 4; ++n) acc[m][n] = (f32x4){0.f, 0.f, 0.f, 0.f};

#define STAGE_A(CH, SL)                                                        \
  {                                                                            \
    _Pragma("unroll") for (int i = 0; i < 2; ++i)                              \
        gload_lds16(asrc[i] + (CH) * 128, smem + (SL) + adst[i]);              \
  }
#define STAGE_B(CH, SL)                                                        \
  {                                                                            \
    const char* wsp = wbuf + (CH) * WIMG;                                      \
    _Pragma("unroll") for (int i = 0; i < 2; ++i)                              \
        gload_lds16(wsp + i * 8192 + tid * 16,                                 \
                    smem + BBASE + (SL) + i * 8192 + tid * 16);                \
  }

  // ---- prologue: A(0), B(0), A(1); vmcnt(2) retires A(0)+B(0) ----
  STAGE_A(0, 0);
  STAGE_B(0, 0);
  STAGE_A(1, ASLOT);
  asm volatile("s_waitcnt vmcnt(2)\n\ts_barrier" ::: "memory");

  unsigned aR = 0;          // A slot of step t (ring of 3)
  unsigned aI = 2 * ASLOT;  // A slot of step t+2
  unsigned bR = 0;          // B slot of step t (ring of 2)

  for (int t = 0; t < KSTEPS; ++t) {
    // issue B(t+1) first (retired this step), then A(t+2) (stays in flight)
    const int tb = (t + 1 < KSTEPS) ? t + 1 : KSTEPS - 1;
    STAGE_B(tb, bR ^ BSLOT);
    const int ta = (t + 2 < KSTEPS) ? t + 2 : KSTEPS - 1;
    STAGE_A(ta, aI);

    // fragments: A fp32 -> pack bf16; B bf16 direct
    const char* Ac = smem + aR;
    const char* Bc = smem + BBASE + bR;
    bf16x8 af[4], bfr[4];
#pragma unroll
    for (int m = 0; m < 4; ++m) {
      const unsigned rb = (unsigned)((wm * 64 + m * 16 + l15) * 128);
      f32x4 u0 = *reinterpret_cast<const f32x4*>(Ac + rb + ((l4 * 32) ^ swA));
      f32x4 u1 = *reinterpret_cast<const f32x4*>(Ac + rb + ((l4 * 32 + 16) ^ swA));
      af[m] = packfrag(u0, u1);
    }
#pragma unroll
    for (int n = 0; n < 4; ++n)
      bfr[n] = *reinterpret_cast<const bf16x8*>(Bc + bbase + n * 1024);

#pragma unroll
    for (int m = 0; m < 4; ++m)
#pragma unroll
      for (int n = 0; n < 4; ++n)
        acc[m][n] = __builtin_amdgcn_mfma_f32_16x16x32_bf16(af[m], bfr[n], acc[m][n], 0, 0, 0);

    // counted wait: retires B(t+1)+A(t+1); A(t+2)'s 2 insts stay in flight
    asm volatile("s_waitcnt vmcnt(2)" ::: "memory");
    asm volatile("s_waitcnt lgkmcnt(0)" ::: "memory");
    __builtin_amdgcn_s_barrier();

    // rotate rings
    aR = (aR == 2 * ASLOT) ? 0u : aR + ASLOT;
    aI = (aI == 2 * ASLOT) ? 0u : aI + ASLOT;
    bR ^= BSLOT;
  }
#undef STAGE_A
#undef STAGE_B

  // drain tail loads before reusing LDS
  asm volatile("s_waitcnt vmcnt(0)" ::: "memory");
  __syncthreads();

  // ---- epilogue (R6-verified): activation -> LDS transpose (1040B pitch) ----
  float bs[4];
#pragma unroll
  for (int n = 0; n < 4; ++n) bs[n] = bias[wn * 64 + n * 16 + l15];

  const int rr2 = tid >> 5;            // 0..15 read-back row
  const int co = (tid & 31) * 8;       // read-back col (floats)
  const char* rdp = smem + rr2 * 1040 + co * 4;

#pragma unroll
  for (int p = 0; p < 8; ++p) {        // band p = rows p*16..+15 (wm group p>>2)
    if ((wid >> 2) == (p >> 2)) {
      const int m = p & 3;
#pragma unroll
      for (int n = 0; n < 4; ++n) {
        const int col = wn * 64 + n * 16 + l15;
        const bool diag = (col % 17) == 0;
#pragma unroll
        for (int j2 = 0; j2 < 4; ++j2) {
          const int rr = l4 * 4 + j2;
          float v = acc[m][n][j2] + bs[n];
          float e = __expf(-fabsf(v));
          float sig = (v >= 0.f) ? 1.f / (1.f + e) : e / (1.f + e);
          float sp = fmaxf(v, 0.f) + __logf(1.f + e);
          *reinterpret_cast<float*>(smem + rr * 1040 + col * 4) = diag ? sig : -sp;
        }
      }
    }
    __syncthreads();
    float4 o0 = *reinterpret_cast<const float4*>(rdp);
    float4 o1 = *reinterpret_cast<const float4*>(rdp + 16);
    float* orow = out + (blkRow + (size_t)(p * 16 + rr2)) * 256 + co;
    *reinterpret_cast<float4*>(orow) = o0;
    *reinterpret_cast<float4*>(orow + 4) = o1;
    __syncthreads();
  }
}

extern "C" void kernel_launch(void* const* d_in, const int* in_sizes, int n_in,
                              void* d_out, int out_size, void* d_ws, size_t ws_size,
                              hipStream_t stream) {
  const float* x = (const float*)d_in[0];
  const float* Wd = (const float*)d_in[1];
  const float* bd = (const float*)d_in[2];
  const float* Wo = (const float*)d_in[3];
  const float* bo = (const float*)d_in[4];
  float* out = (float*)d_out;
  char* wbuf = (char*)d_ws;                  // 512 KiB weight image
  float* bias = (float*)(wbuf + WBYTES);     // 1 KiB bias

  prep_kernel<<<dim3(256), dim3(256), 0, stream>>>(Wd, bd, Wo, bo, wbuf, bias);
  cap_main<<<dim3(512), dim3(THREADS), 0, stream>>>(x, wbuf, bias, out);
}

// Round 18
// 100.196 us; speedup vs baseline: 2.3056x; 1.0283x over previous
//
#include <hip/hip_runtime.h>
#include <hip/hip_bf16.h>
#include <stdint.h>

// C = (B,16,16): diag (k,k)=sigmoid(x·Wd[k]+bd[k]); off (i,j)=-softplus(x·Wo[r]+bo[r])
// Permuted GEMM out[b][c], c=i*16+j. M=65536 N=256 K=1024, bf16 MFMA 16x16x32.
// R18 = R17 (best: 103.0 us) with pack2 bit-twiddle replaced by scalar __bf16
// casts -> compiler emits v_cvt_pk_bf16_f32 (1 op / 2 floats vs 5 ops): cuts
// ~40% of per-step VALU on the barrier-to-barrier critical chain.
// Structure: BM=128, 512 blocks x 512 thr (8 waves, 2Mx4N). A fp32 via
// gload_lds (3-slot ring, 2-step cover, pre-swizzled source); B via gload_lds
// (2-slot ring, 1-step cover). Per step: issue B(t+1), A(t+2); after MFMA wait
// vmcnt(2) (retire A(t+1)+B(t+1), keep A(t+2) in flight across raw barrier).
// LDS 80 KB -> 2 blocks/CU.

typedef __bf16 bf16x8 __attribute__((ext_vector_type(8)));
typedef float f32x4 __attribute__((ext_vector_type(4)));

#define THREADS 512
#define BM 128
#define KSTEPS 32
#define WIMG 16384                 // per-K-step B image: 256 cols x 32 k x 2B
#define WBYTES (WIMG * KSTEPS)     // 512 KiB

#define ASLOT 16384                // A slot: 128 rows x 32 k x 4B fp32 (swizzled)
#define BBASE 49152                // A slots @0,16K,32K ; B slots @48K,64K
#define BSLOT 16384
#define SMEM_SZ 81920              // 80 KiB -> 2 blocks/CU

__device__ __forceinline__ unsigned bf_rtne(unsigned u) {
  return (u + 0x7fffu + ((u >> 16) & 1u)) >> 16;
}
__device__ __forceinline__ unsigned pack2(float lo, float hi) {
  return bf_rtne(__float_as_uint(lo)) | (bf_rtne(__float_as_uint(hi)) << 16);
}
// A-fragment pack: scalar casts -> compiler fuses into v_cvt_pk_bf16_f32 (RTNE)
__device__ __forceinline__ bf16x8 packfrag(const f32x4& a, const f32x4& b) {
  bf16x8 r;
  r[0] = (__bf16)a[0]; r[1] = (__bf16)a[1]; r[2] = (__bf16)a[2]; r[3] = (__bf16)a[3];
  r[4] = (__bf16)b[0]; r[5] = (__bf16)b[1]; r[6] = (__bf16)b[2]; r[7] = (__bf16)b[3];
  return r;
}
__device__ __forceinline__ void gload_lds16(const void* g, void* l) {
  __builtin_amdgcn_global_load_lds(
      (const __attribute__((address_space(1))) unsigned int*)g,
      (__attribute__((address_space(3))) unsigned int*)l, 16, 0, 0);
}

// B image per K-step (R4/R12-verified): byte(c,k)=(c*64+k*2)^(((c>>1)&3)<<4)
__global__ void prep_kernel(const float* __restrict__ Wd, const float* __restrict__ bd,
                            const float* __restrict__ Wo, const float* __restrict__ bo,
                            char* __restrict__ wbuf, float* __restrict__ bias) {
  const int c = blockIdx.x;    // 0..255 output col
  const int t = threadIdx.x;   // 0..255, 4 consecutive k each
  const int i = c >> 4, j = c & 15;
  const float* src;
  float b;
  if (i == j) { src = Wd + i * 1024; b = bd[i]; }
  else { int r = i * 15 + (j < i ? j : j - 1); src = Wo + r * 1024; b = bo[r]; }
  if (t == 0) bias[c] = b;
  const int kk = t * 4;
  const int img = kk >> 5, k5 = kk & 31;
  float4 v = *reinterpret_cast<const float4*>(src + kk);
  uint2 h;
  h.x = pack2(v.x, v.y);
  h.y = pack2(v.z, v.w);
  const unsigned off = (unsigned)((c * 64 + k5 * 2) ^ (((c >> 1) & 3) << 4));
  *reinterpret_cast<uint2*>(wbuf + img * WIMG + off) = h;
}

__global__ __launch_bounds__(THREADS, 4) void cap_main(
    const float* __restrict__ x, const char* __restrict__ wbuf,
    const float* __restrict__ bias, float* __restrict__ out) {
  __shared__ char smem[SMEM_SZ];

  const int tid = threadIdx.x;
  const int wid = tid >> 6;
  const int lane = tid & 63;
  const int l15 = lane & 15;
  const int l4 = lane >> 4;
  const int wm = wid >> 2;       // 0..1: rows wm*64..+63
  const int wn = wid & 3;        // 0..3: cols wn*64..+63

  const size_t blkRow = (size_t)blockIdx.x * BM;

  // ---- A staging map (2 insts/thread; 512 thr x 16B x 2 = 16 KB slot) ----
  // inst i: dest d = i*8192 + tid*16 ; row = i*64 + (tid>>3) ; col = (tid&7)*16
  // LDS layout byte(row,kb) = row*128 + (kb ^ ((row&7)<<4)) -> pre-swizzle src.
  const unsigned acol = (unsigned)(((tid & 7) * 16) ^ (((tid >> 3) & 7) << 4));
  const char* asrc[2];
  unsigned adst[2];
#pragma unroll
  for (int i = 0; i < 2; ++i) {
    const int row = i * 64 + (tid >> 3);
    asrc[i] = (const char*)(x + (blkRow + (size_t)row) * 1024) + acol;
    adst[i] = (unsigned)(i * 8192 + tid * 16);
  }

  // ---- fragment read bases ----
  const unsigned swA = (unsigned)((l15 & 7) << 4);
  const unsigned bbase = (unsigned)(wn * 4096 + l15 * 64 +
                                    ((l4 * 16) ^ (((l15 >> 1) & 3) << 4)));

  f32x4 acc[4][4];
#pragma unroll
  for (int m = 0; m < 4; ++m)
#pragma unroll
    for (int n = 0; n < 4; ++n) acc[m][n] = (f32x4){0.f, 0.f, 0.f, 0.f};

#define STAGE_A(CH, SL)                                                        \
  {                                                                            \
    _Pragma("unroll") for (int i = 0; i < 2; ++i)                              \
        gload_lds16(asrc[i] + (CH) * 128, smem + (SL) + adst[i]);              \
  }
#define STAGE_B(CH, SL)                                                        \
  {                                                                            \
    const char* wsp = wbuf + (CH) * WIMG;                                      \
    _Pragma("unroll") for (int i = 0; i < 2; ++i)                              \
        gload_lds16(wsp + i * 8192 + tid * 16,                                 \
                    smem + BBASE + (SL) + i * 8192 + tid * 16);                \
  }

  // ---- prologue: A(0), B(0), A(1); vmcnt(2) retires A(0)+B(0) ----
  STAGE_A(0, 0);
  STAGE_B(0, 0);
  STAGE_A(1, ASLOT);
  asm volatile("s_waitcnt vmcnt(2)\n\ts_barrier" ::: "memory");

  unsigned aR = 0;          // A slot of step t (ring of 3)
  unsigned aI = 2 * ASLOT;  // A slot of step t+2
  unsigned bR = 0;          // B slot of step t (ring of 2)

  for (int t = 0; t < KSTEPS; ++t) {
    // issue B(t+1) first (retired this step), then A(t+2) (stays in flight)
    const int tb = (t + 1 < KSTEPS) ? t + 1 : KSTEPS - 1;
    STAGE_B(tb, bR ^ BSLOT);
    const int ta = (t + 2 < KSTEPS) ? t + 2 : KSTEPS - 1;
    STAGE_A(ta, aI);

    // fragments: A fp32 -> cvt_pk bf16; B bf16 direct
    const char* Ac = smem + aR;
    const char* Bc = smem + BBASE + bR;
    bf16x8 af[4], bfr[4];
#pragma unroll
    for (int m = 0; m < 4; ++m) {
      const unsigned rb = (unsigned)((wm * 64 + m * 16 + l15) * 128);
      f32x4 u0 = *reinterpret_cast<const f32x4*>(Ac + rb + ((l4 * 32) ^ swA));
      f32x4 u1 = *reinterpret_cast<const f32x4*>(Ac + rb + ((l4 * 32 + 16) ^ swA));
      af[m] = packfrag(u0, u1);
    }
#pragma unroll
    for (int n = 0; n < 4; ++n)
      bfr[n] = *reinterpret_cast<const bf16x8*>(Bc + bbase + n * 1024);

#pragma unroll
    for (int m = 0; m < 4; ++m)
#pragma unroll
      for (int n = 0; n < 4; ++n)
        acc[m][n] = __builtin_amdgcn_mfma_f32_16x16x32_bf16(af[m], bfr[n], acc[m][n], 0, 0, 0);

    // counted wait: retires B(t+1)+A(t+1); A(t+2)'s 2 insts stay in flight
    asm volatile("s_waitcnt vmcnt(2)" ::: "memory");
    asm volatile("s_waitcnt lgkmcnt(0)" ::: "memory");
    __builtin_amdgcn_s_barrier();

    // rotate rings
    aR = (aR == 2 * ASLOT) ? 0u : aR + ASLOT;
    aI = (aI == 2 * ASLOT) ? 0u : aI + ASLOT;
    bR ^= BSLOT;
  }
#undef STAGE_A
#undef STAGE_B

  // drain tail loads before reusing LDS
  asm volatile("s_waitcnt vmcnt(0)" ::: "memory");
  __syncthreads();

  // ---- epilogue (R6-verified): activation -> LDS transpose (1040B pitch) ----
  float bs[4];
#pragma unroll
  for (int n = 0; n < 4; ++n) bs[n] = bias[wn * 64 + n * 16 + l15];

  const int rr2 = tid >> 5;            // 0..15 read-back row
  const int co = (tid & 31) * 8;       // read-back col (floats)
  const char* rdp = smem + rr2 * 1040 + co * 4;

#pragma unroll
  for (int p = 0; p < 8; ++p) {        // band p = rows p*16..+15 (wm group p>>2)
    if ((wid >> 2) == (p >> 2)) {
      const int m = p & 3;
#pragma unroll
      for (int n = 0; n < 4; ++n) {
        const int col = wn * 64 + n * 16 + l15;
        const bool diag = (col % 17) == 0;
#pragma unroll
        for (int j2 = 0; j2 < 4; ++j2) {
          const int rr = l4 * 4 + j2;
          float v = acc[m][n][j2] + bs[n];
          float e = __expf(-fabsf(v));
          float sig = (v >= 0.f) ? 1.f / (1.f + e) : e / (1.f + e);
          float sp = fmaxf(v, 0.f) + __logf(1.f + e);
          *reinterpret_cast<float*>(smem + rr * 1040 + col * 4) = diag ? sig : -sp;
        }
      }
    }
    __syncthreads();
    float4 o0 = *reinterpret_cast<const float4*>(rdp);
    float4 o1 = *reinterpret_cast<const float4*>(rdp + 16);
    float* orow = out + (blkRow + (size_t)(p * 16 + rr2)) * 256 + co;
    *reinterpret_cast<float4*>(orow) = o0;
    *reinterpret_cast<float4*>(orow + 4) = o1;
    __syncthreads();
  }
}

extern "C" void kernel_launch(void* const* d_in, const int* in_sizes, int n_in,
                              void* d_out, int out_size, void* d_ws, size_t ws_size,
                              hipStream_t stream) {
  const float* x = (const float*)d_in[0];
  const float* Wd = (const float*)d_in[1];
  const float* bd = (const float*)d_in[2];
  const float* Wo = (const float*)d_in[3];
  const float* bo = (const float*)d_in[4];
  float* out = (float*)d_out;
  char* wbuf = (char*)d_ws;                  // 512 KiB weight image
  float* bias = (float*)(wbuf + WBYTES);     // 1 KiB bias

  prep_kernel<<<dim3(256), dim3(256), 0, stream>>>(Wd, bd, Wo, bo, wbuf, bias);
  cap_main<<<dim3(512), dim3(THREADS), 0, stream>>>(x, wbuf, bias, out);
}